// Round 3
// baseline (4299.888 us; speedup 1.0000x reference)
//
#include <hip/hip_runtime.h>
#include <math.h>

#define M_ROWS 2048
#define N_COLS 2048
#define DIMS 512
#define IN_STRIDE 513

constexpr float GAMMA = 0.001f;

// ---------------- argsort by timestamp (last column), stable ----------------
__global__ void argsort_kernel(const float* __restrict__ a, const float* __restrict__ b,
                               int* __restrict__ permA, int* __restrict__ permB) {
    const float* src = blockIdx.y ? b : a;
    int* perm = blockIdx.y ? permB : permA;
    __shared__ float keys[M_ROWS];
    for (int j = threadIdx.x; j < M_ROWS; j += blockDim.x)
        keys[j] = src[(size_t)j * IN_STRIDE + DIMS];
    __syncthreads();
    int i = blockIdx.x * blockDim.x + threadIdx.x;
    float ki = keys[i];
    int rank = 0;
    for (int j = 0; j < M_ROWS; ++j) {
        float kj = keys[j];
        rank += (kj < ki) || (kj == ki && j < i);  // stable rank
    }
    perm[rank] = i;
}

// ---------------- gather sorted rows + L2-normalize (drop time col) ----------------
__global__ __launch_bounds__(128) void norm_kernel(const float* __restrict__ a, const float* __restrict__ b,
                                                   const int* __restrict__ permA, const int* __restrict__ permB,
                                                   float* __restrict__ Ahat, float* __restrict__ Bhat) {
    const float* src = blockIdx.y ? b : a;
    const int* perm = blockIdx.y ? permB : permA;
    float* dst = blockIdx.y ? Bhat : Ahat;
    int r = blockIdx.x;
    int row = perm[r];
    const float* p = src + (size_t)row * IN_STRIDE;
    int tid = threadIdx.x;
    float v0 = p[tid], v1 = p[tid + 128], v2 = p[tid + 256], v3 = p[tid + 384];
    float ss = v0 * v0 + v1 * v1 + v2 * v2 + v3 * v3;
    #pragma unroll
    for (int off = 32; off > 0; off >>= 1) ss += __shfl_down(ss, off);
    __shared__ float red[2];
    if ((tid & 63) == 0) red[tid >> 6] = ss;
    __syncthreads();
    float inv = 1.0f / sqrtf(red[0] + red[1] + 1e-10f);
    float* q = dst + (size_t)r * DIMS;
    q[tid] = v0 * inv; q[tid + 128] = v1 * inv; q[tid + 256] = v2 * inv; q[tid + 384] = v3 * inv;
}

// ---------------- GEMM: Q[i][n] = exp(-1 - dot(Ahat[i], Bhat[n])) = exp(cost-2) ----------------
__global__ __launch_bounds__(256) void gemm_kernel(const float* __restrict__ A, const float* __restrict__ B,
                                                   float* __restrict__ Q) {
    __shared__ float As[16][68];
    __shared__ float Bs[16][68];
    int tid = threadIdx.x;
    int tx = tid & 15, ty = tid >> 4;
    int row0 = blockIdx.y * 64;
    int col0 = blockIdx.x * 64;
    int lrow = tid >> 2;          // 0..63
    int lk = (tid & 3) * 4;       // 0,4,8,12
    const float* ap = A + (size_t)(row0 + lrow) * DIMS + lk;
    const float* bp = B + (size_t)(col0 + lrow) * DIMS + lk;
    float acc[4][4] = {};
    for (int k0 = 0; k0 < DIMS; k0 += 16) {
        float4 av = *(const float4*)ap; ap += 16;
        float4 bv = *(const float4*)bp; bp += 16;
        __syncthreads();
        As[lk + 0][lrow] = av.x; As[lk + 1][lrow] = av.y; As[lk + 2][lrow] = av.z; As[lk + 3][lrow] = av.w;
        Bs[lk + 0][lrow] = bv.x; Bs[lk + 1][lrow] = bv.y; Bs[lk + 2][lrow] = bv.z; Bs[lk + 3][lrow] = bv.w;
        __syncthreads();
        #pragma unroll
        for (int k = 0; k < 16; ++k) {
            float4 a4 = *(const float4*)&As[k][ty * 4];
            float4 b4 = *(const float4*)&Bs[k][tx * 4];
            float aa[4] = {a4.x, a4.y, a4.z, a4.w};
            float bb[4] = {b4.x, b4.y, b4.z, b4.w};
            #pragma unroll
            for (int u = 0; u < 4; ++u)
                #pragma unroll
                for (int v = 0; v < 4; ++v)
                    acc[u][v] += aa[u] * bb[v];
        }
    }
    #pragma unroll
    for (int u = 0; u < 4; ++u) {
        float4 o;
        o.x = __expf(-1.0f - acc[u][0]);
        o.y = __expf(-1.0f - acc[u][1]);
        o.z = __expf(-1.0f - acc[u][2]);
        o.w = __expf(-1.0f - acc[u][3]);
        *(float4*)&Q[(size_t)(row0 + ty * 4 + u) * N_COLS + col0 + tx * 4] = o;
    }
}

// ---------------- per-row softmax denom -> rowscale rs = 1/(gamma*denom) ----------------
// C_even = 1/denom -> log We = -rs ; C_odd = Q/denom -> log Wo = -rs*Q
__global__ __launch_bounds__(256) void rowstat_kernel(const float* __restrict__ Q,
                                                      float* __restrict__ rowscale) {
    int i = blockIdx.x;
    const float* q = Q + (size_t)i * N_COLS;
    int tid = threadIdx.x;
    float4 x = *(const float4*)(q + tid * 4);
    float4 y = *(const float4*)(q + 1024 + tid * 4);
    float s = x.x + x.y + x.z + x.w + y.x + y.y + y.z + y.w;
    #pragma unroll
    for (int off = 32; off > 0; off >>= 1) s += __shfl_down(s, off);
    __shared__ float red[4];
    if ((tid & 63) == 0) red[tid >> 6] = s;
    __syncthreads();
    if (tid == 0) {
        float denom = 2049.0f + red[0] + red[1] + red[2] + red[3];
        rowscale[i] = (1.0f / GAMMA) / denom;
    }
}

// ---------------- LWo[i][n] = -rs_i * Q[i][n]  (log of odd-column weight), in place ----------------
__global__ __launch_bounds__(256) void lwo_kernel(float* __restrict__ Q, const float* __restrict__ rowscale) {
    int e = blockIdx.x * blockDim.x + threadIdx.x;   // float4 index
    float rs = rowscale[e >> 9];
    float4 x = *(float4*)(Q + (size_t)e * 4);
    x.x = -rs * x.x; x.y = -rs * x.y; x.z = -rs * x.z; x.w = -rs * x.w;
    *(float4*)(Q + (size_t)e * 4) = x;
}

// ---------------- log-sum-exp helpers on (m, s) pairs: value = m + log(s) ----------------
__device__ __forceinline__ void lse_acc(float& m, float& s, float m2, float s2) {
    float M = fmaxf(m, m2);
    s = s * __expf(m - M) + s2 * __expf(m2 - M);
    m = M;
}
__device__ __forceinline__ void lse_acc1(float& m, float& s, float v) {
    float M = fmaxf(m, v);
    s = s * __expf(m - M) + __expf(v - M);
    m = M;
}

// ---------------- sequential DP, LOG-DOMAIN (stable prefix LSE per row) ----------------
// d[j] = log E_i[j]. Within-row dynamic range is ~1000 nats (race-to-top vs saddle band),
// so linear-domain fp32/fp64 both flush the paths that dominate the final answer.
// Thread t holds columns 8t..8t+7; implicit column 4096 tracked as scalar h (same on all threads).
// Per row: prefix-LSE S over prev d; new d[2k] = -rs_i + S[8t+2k]; d[2k+1] = LWo + S[8t+2k].
__global__ __launch_bounds__(512) void dp_kernel(const float* __restrict__ LWo,
                                                 const float* __restrict__ Rs,
                                                 float* __restrict__ out) {
    const int tid = threadIdx.x;
    const int lane = tid & 63;
    const int wid = tid >> 6;        // 0..7
    __shared__ float2 wtot[2][8];
    __shared__ float sRs[M_ROWS];
    for (int k = tid; k < M_ROWS; k += 512) sRs[k] = Rs[k];
    __syncthreads();

    float d[8];
    float h;
    {
        float rs0 = sRs[0];
        float4 w = *(const float4*)(LWo + 4 * tid);
        d[0] = -rs0; d[1] = w.x; d[2] = -rs0; d[3] = w.y;
        d[4] = -rs0; d[5] = w.z; d[6] = -rs0; d[7] = w.w;
        h = -rs0;    // column 4096
    }
    float4 nw = *(const float4*)(LWo + (size_t)N_COLS + 4 * tid);  // prefetch row 1

    for (int i = 1; i < M_ROWS; ++i) {
        float rsi = sRs[i];
        float4 cw = nw;
        if (i + 1 < M_ROWS) nw = *(const float4*)(LWo + (size_t)(i + 1) * N_COLS + 4 * tid);

        // thread-local LSE of d[0..7]
        float mq = d[0];
        #pragma unroll
        for (int k = 1; k < 8; ++k) mq = fmaxf(mq, d[k]);
        float sq = 0.f;
        #pragma unroll
        for (int k = 0; k < 8; ++k) sq += __expf(d[k] - mq);

        // warp inclusive LSE-scan
        float mi = mq, si = sq;
        #pragma unroll
        for (int off = 1; off < 64; off <<= 1) {
            float mp = __shfl_up(mi, off);
            float sp = __shfl_up(si, off);
            if (lane >= off) lse_acc(mi, si, mp, sp);
        }
        // exclusive via shift-by-1
        float me = __shfl_up(mi, 1), se = __shfl_up(si, 1);
        if (lane == 0) { me = -1e30f; se = 0.f; }
        float2* wt = wtot[i & 1];
        if (lane == 63) wt[wid] = make_float2(mi, si);
        __syncthreads();

        // fold earlier warps into exclusive prefix; fold all warps (+h) into row total
        float mb = me, sb = se;
        float mT = -1e30f, sT = 0.f;
        #pragma unroll
        for (int wf = 0; wf < 8; ++wf) {
            float2 v = wt[wf];
            if (wf < wid) lse_acc(mb, sb, v.x, v.y);
            lse_acc(mT, sT, v.x, v.y);
        }
        lse_acc1(mT, sT, h);

        // within-thread sequential prefix over OLD d; S needed at even offsets 0,2,4,6
        float v0, v1, v2, v3;
        lse_acc1(mb, sb, d[0]); v0 = mb + __logf(sb);
        lse_acc1(mb, sb, d[1]);
        lse_acc1(mb, sb, d[2]); v1 = mb + __logf(sb);
        lse_acc1(mb, sb, d[3]);
        lse_acc1(mb, sb, d[4]); v2 = mb + __logf(sb);
        lse_acc1(mb, sb, d[5]);
        lse_acc1(mb, sb, d[6]); v3 = mb + __logf(sb);

        d[0] = -rsi + v0; d[1] = cw.x + v0;
        d[2] = -rsi + v1; d[3] = cw.y + v1;
        d[4] = -rsi + v2; d[5] = cw.z + v2;
        d[6] = -rsi + v3; d[7] = cw.w + v3;
        h = -rsi + (mT + __logf(sT));   // E[4096] sees full-row prefix = total
    }

    // final LSE over all d + h
    {
        float mq = d[0];
        #pragma unroll
        for (int k = 1; k < 8; ++k) mq = fmaxf(mq, d[k]);
        float sq = 0.f;
        #pragma unroll
        for (int k = 0; k < 8; ++k) sq += __expf(d[k] - mq);
        // butterfly LSE-reduce across the wave
        #pragma unroll
        for (int off = 1; off < 64; off <<= 1) {
            float mp = __shfl_xor(mq, off);
            float sp = __shfl_xor(sq, off);
            lse_acc(mq, sq, mp, sp);
        }
        if (lane == 0) wtot[0][wid] = make_float2(mq, sq);
        __syncthreads();
        if (tid == 0) {
            float mT = -1e30f, sT = 0.f;
            #pragma unroll
            for (int wf = 0; wf < 8; ++wf) lse_acc(mT, sT, wtot[0][wf].x, wtot[0][wf].y);
            lse_acc1(mT, sT, h);
            out[0] = -GAMMA * (mT + __logf(sT));
        }
    }
}

extern "C" void kernel_launch(void* const* d_in, const int* in_sizes, int n_in,
                              void* d_out, int out_size, void* d_ws, size_t ws_size,
                              hipStream_t stream) {
    (void)in_sizes; (void)n_in; (void)out_size; (void)ws_size;
    const float* a = (const float*)d_in[0];
    const float* b = (const float*)d_in[1];
    float* out = (float*)d_out;
    char* ws = (char*)d_ws;
    float* Q        = (float*)(ws);                                    // 16 MB (Q, then LWo in place)
    float* Ahat     = (float*)(ws + (size_t)16 * 1024 * 1024);         // 4 MB
    float* Bhat     = (float*)(ws + (size_t)20 * 1024 * 1024);         // 4 MB
    float* rowscale = (float*)(ws + (size_t)24 * 1024 * 1024);         // 8 KB
    int* permA      = (int*)(ws + (size_t)24 * 1024 * 1024 + 8192);    // 8 KB
    int* permB      = (int*)(ws + (size_t)24 * 1024 * 1024 + 16384);   // 8 KB

    argsort_kernel<<<dim3(8, 2), 256, 0, stream>>>(a, b, permA, permB);
    norm_kernel<<<dim3(2048, 2), 128, 0, stream>>>(a, b, permA, permB, Ahat, Bhat);
    gemm_kernel<<<dim3(32, 32), 256, 0, stream>>>(Ahat, Bhat, Q);
    rowstat_kernel<<<2048, 256, 0, stream>>>(Q, rowscale);
    lwo_kernel<<<4096, 256, 0, stream>>>(Q, rowscale);
    dp_kernel<<<1, 512, 0, stream>>>(Q, rowscale, out);
}

// Round 5
// 2456.559 us; speedup vs baseline: 1.7504x; 1.7504x over previous
//
#include <hip/hip_runtime.h>
#include <math.h>

#define M_ROWS 2048
#define N_COLS 2048
#define DIMS 512
#define IN_STRIDE 513

constexpr float GAMMA = 0.001f;
constexpr float LOG2E = 1.44269504088896f;
constexpr float LN2   = 0.69314718055995f;

// hardware base-2 exp/log (v_exp_f32 / v_log_f32). NOTE: __exp2f/__log2f collide
// with glibc math.h internals on this toolchain — use the amdgcn builtins.
__device__ __forceinline__ float fexp2(float x) { return __builtin_amdgcn_exp2f(x); }
__device__ __forceinline__ float flog2(float x) { return __builtin_amdgcn_logf(x); }

// ---------------- argsort by timestamp (last column), stable ----------------
__global__ void argsort_kernel(const float* __restrict__ a, const float* __restrict__ b,
                               int* __restrict__ permA, int* __restrict__ permB) {
    const float* src = blockIdx.y ? b : a;
    int* perm = blockIdx.y ? permB : permA;
    __shared__ float keys[M_ROWS];
    for (int j = threadIdx.x; j < M_ROWS; j += blockDim.x)
        keys[j] = src[(size_t)j * IN_STRIDE + DIMS];
    __syncthreads();
    int i = blockIdx.x * blockDim.x + threadIdx.x;
    float ki = keys[i];
    int rank = 0;
    for (int j = 0; j < M_ROWS; ++j) {
        float kj = keys[j];
        rank += (kj < ki) || (kj == ki && j < i);  // stable rank
    }
    perm[rank] = i;
}

// ---------------- gather sorted rows + L2-normalize (drop time col) ----------------
__global__ __launch_bounds__(128) void norm_kernel(const float* __restrict__ a, const float* __restrict__ b,
                                                   const int* __restrict__ permA, const int* __restrict__ permB,
                                                   float* __restrict__ Ahat, float* __restrict__ Bhat) {
    const float* src = blockIdx.y ? b : a;
    const int* perm = blockIdx.y ? permB : permA;
    float* dst = blockIdx.y ? Bhat : Ahat;
    int r = blockIdx.x;
    int row = perm[r];
    const float* p = src + (size_t)row * IN_STRIDE;
    int tid = threadIdx.x;
    float v0 = p[tid], v1 = p[tid + 128], v2 = p[tid + 256], v3 = p[tid + 384];
    float ss = v0 * v0 + v1 * v1 + v2 * v2 + v3 * v3;
    #pragma unroll
    for (int off = 32; off > 0; off >>= 1) ss += __shfl_down(ss, off);
    __shared__ float red[2];
    if ((tid & 63) == 0) red[tid >> 6] = ss;
    __syncthreads();
    float inv = 1.0f / sqrtf(red[0] + red[1] + 1e-10f);
    float* q = dst + (size_t)r * DIMS;
    q[tid] = v0 * inv; q[tid + 128] = v1 * inv; q[tid + 256] = v2 * inv; q[tid + 384] = v3 * inv;
}

// ---------------- GEMM: Q[i][n] = exp(-1 - dot(Ahat[i], Bhat[n])) = exp(cost-2) ----------------
__global__ __launch_bounds__(256) void gemm_kernel(const float* __restrict__ A, const float* __restrict__ B,
                                                   float* __restrict__ Q) {
    __shared__ float As[16][68];
    __shared__ float Bs[16][68];
    int tid = threadIdx.x;
    int tx = tid & 15, ty = tid >> 4;
    int row0 = blockIdx.y * 64;
    int col0 = blockIdx.x * 64;
    int lrow = tid >> 2;          // 0..63
    int lk = (tid & 3) * 4;       // 0,4,8,12
    const float* ap = A + (size_t)(row0 + lrow) * DIMS + lk;
    const float* bp = B + (size_t)(col0 + lrow) * DIMS + lk;
    float acc[4][4] = {};
    for (int k0 = 0; k0 < DIMS; k0 += 16) {
        float4 av = *(const float4*)ap; ap += 16;
        float4 bv = *(const float4*)bp; bp += 16;
        __syncthreads();
        As[lk + 0][lrow] = av.x; As[lk + 1][lrow] = av.y; As[lk + 2][lrow] = av.z; As[lk + 3][lrow] = av.w;
        Bs[lk + 0][lrow] = bv.x; Bs[lk + 1][lrow] = bv.y; Bs[lk + 2][lrow] = bv.z; Bs[lk + 3][lrow] = bv.w;
        __syncthreads();
        #pragma unroll
        for (int k = 0; k < 16; ++k) {
            float4 a4 = *(const float4*)&As[k][ty * 4];
            float4 b4 = *(const float4*)&Bs[k][tx * 4];
            float aa[4] = {a4.x, a4.y, a4.z, a4.w};
            float bb[4] = {b4.x, b4.y, b4.z, b4.w};
            #pragma unroll
            for (int u = 0; u < 4; ++u)
                #pragma unroll
                for (int v = 0; v < 4; ++v)
                    acc[u][v] += aa[u] * bb[v];
        }
    }
    #pragma unroll
    for (int u = 0; u < 4; ++u) {
        float4 o;
        o.x = __expf(-1.0f - acc[u][0]);
        o.y = __expf(-1.0f - acc[u][1]);
        o.z = __expf(-1.0f - acc[u][2]);
        o.w = __expf(-1.0f - acc[u][3]);
        *(float4*)&Q[(size_t)(row0 + ty * 4 + u) * N_COLS + col0 + tx * 4] = o;
    }
}

// ---------------- per-row softmax denom -> rs2 = log2e/(gamma*denom) ----------------
// log2 We = -rs2 ; log2 Wo[n] = -rs2*Q[n]
__global__ __launch_bounds__(256) void rowstat_kernel(const float* __restrict__ Q,
                                                      float* __restrict__ rowscale) {
    int i = blockIdx.x;
    const float* q = Q + (size_t)i * N_COLS;
    int tid = threadIdx.x;
    float4 x = *(const float4*)(q + tid * 4);
    float4 y = *(const float4*)(q + 1024 + tid * 4);
    float s = x.x + x.y + x.z + x.w + y.x + y.y + y.z + y.w;
    #pragma unroll
    for (int off = 32; off > 0; off >>= 1) s += __shfl_down(s, off);
    __shared__ float red[4];
    if ((tid & 63) == 0) red[tid >> 6] = s;
    __syncthreads();
    if (tid == 0) {
        float denom = 2049.0f + red[0] + red[1] + red[2] + red[3];
        rowscale[i] = (LOG2E / GAMMA) / denom;
    }
}

// ---------------- LG2[i][n] = log2(We_i + Wo_i[n]) in place over Q ----------------
__device__ __forceinline__ float lse2pair(float a, float b) {
    float M = fmaxf(a, b);
    return M + flog2(fexp2(a - M) + fexp2(b - M));
}
__global__ __launch_bounds__(256) void lg_kernel(float* __restrict__ Q, const float* __restrict__ rowscale) {
    int e = blockIdx.x * blockDim.x + threadIdx.x;   // float4 index
    float rs2 = rowscale[e >> 9];
    float a = -rs2;                                   // log2 We
    float4 x = *(float4*)(Q + (size_t)e * 4);
    x.x = lse2pair(a, -rs2 * x.x);
    x.y = lse2pair(a, -rs2 * x.y);
    x.z = lse2pair(a, -rs2 * x.z);
    x.w = lse2pair(a, -rs2 * x.w);
    *(float4*)(Q + (size_t)e * 4) = x;
}

// ---------------- (m,s) log2-sum-exp combine: value = m + log2(s) ----------------
// one-transcendental version: e = 2^-|m-m2|; select which side gets scaled.
__device__ __forceinline__ void lse1(float& m, float& s, float m2, float s2) {
    float e = fexp2(-fabsf(m - m2));
    float sa = fmaf(s2, e, s);    // m >= m2
    float sb = fmaf(s, e, s2);    // m <  m2
    bool c = m >= m2;
    s = c ? sa : sb;
    m = c ? m : m2;
}
// value of (m,s) ⊕ (v,1) without mutating the pair
__device__ __forceinline__ float cval(float m, float s, float v) {
    float e = fexp2(-fabsf(m - v));
    float sa = s + e;
    float sb = fmaf(s, e, 1.0f);
    bool c = m >= v;
    return fmaxf(m, v) + flog2(c ? sa : sb);
}

// ---------------- sequential DP, even-column fold, log2 domain ----------------
// P[n] = log2 of prefix-sum of prev E-row through even column 2n (n = 0..2047 across
// 512 threads x 4; P[2048] = h, thread 511 only). Per row i:
//   g[m]    = LG2_i[m] + P_old[m]
//   P_new[n]= LSE(excl-prefix(g)[n], LWe2_i + P_old[n])
//   h_new   = LSE(total(g), LWe2_i + h_old)        [thread 511]
// Init P = 0, h = 0 acts as virtual row -1; loop runs all 2048 rows; loss = -g*ln2*h.
__global__ __launch_bounds__(512) void dp_kernel(const float* __restrict__ LG2,
                                                 const float* __restrict__ Rs,
                                                 float* __restrict__ out) {
    const int tid = threadIdx.x;
    const int lane = tid & 63;
    const int wid = tid >> 6;        // 0..7
    __shared__ float2 wtot[2][8];
    __shared__ float sRs[M_ROWS];
    for (int k = tid; k < M_ROWS; k += 512) sRs[k] = Rs[k];
    __syncthreads();

    float P0 = 0.f, P1 = 0.f, P2 = 0.f, P3 = 0.f;
    float h = 0.f;
    float4 nw = *(const float4*)(LG2 + 4 * tid);   // prefetch row 0

    for (int i = 0; i < M_ROWS; ++i) {
        float lwe = -sRs[i];
        float4 cw = nw;
        if (i + 1 < M_ROWS) nw = *(const float4*)(LG2 + (size_t)(i + 1) * N_COLS + 4 * tid);

        float g0 = cw.x + P0, g1 = cw.y + P1, g2 = cw.z + P2, g3 = cw.w + P3;

        // thread-local LSE of g0..g3
        float mq = fmaxf(fmaxf(g0, g1), fmaxf(g2, g3));
        float sq = fexp2(g0 - mq) + fexp2(g1 - mq) + fexp2(g2 - mq) + fexp2(g3 - mq);

        // warp inclusive LSE-scan on (m,s)
        float mi = mq, si = sq;
        #pragma unroll
        for (int off = 1; off < 64; off <<= 1) {
            float mp = __shfl_up(mi, off);
            float sp = __shfl_up(si, off);
            if (lane >= off) lse1(mi, si, mp, sp);
        }
        // exclusive via shift
        float me = __shfl_up(mi, 1), se = __shfl_up(si, 1);
        if (lane == 0) { me = -1e30f; se = 0.f; }
        float2* wt = wtot[i & 1];
        if (lane == 63) wt[wid] = make_float2(mi, si);
        __syncthreads();

        // fold earlier waves' totals into my exclusive base (wave-uniform trip count)
        float cm = me, cs = se;
        for (int wf = 0; wf < wid; ++wf) {
            float2 v = wt[wf];
            lse1(cm, cs, v.x, v.y);
        }

        // positions 4t..4t+3: P_new = (excl ⊕ (lwe+P_old)); extend chain with g
        float v0 = lwe + P0, v1 = lwe + P1, v2 = lwe + P2, v3 = lwe + P3;
        P0 = cval(cm, cs, v0); lse1(cm, cs, g0, 1.0f);
        P1 = cval(cm, cs, v1); lse1(cm, cs, g1, 1.0f);
        P2 = cval(cm, cs, v2); lse1(cm, cs, g2, 1.0f);
        P3 = cval(cm, cs, v3);
        if (wid == 7) {                 // only the last wave needs the row total (for h)
            lse1(cm, cs, g3, 1.0f);     // tid 511: cm/cs = inclusive total of g
            h = cval(cm, cs, lwe + h);
        }
    }
    if (tid == 511) out[0] = -GAMMA * LN2 * h;
}

extern "C" void kernel_launch(void* const* d_in, const int* in_sizes, int n_in,
                              void* d_out, int out_size, void* d_ws, size_t ws_size,
                              hipStream_t stream) {
    (void)in_sizes; (void)n_in; (void)out_size; (void)ws_size;
    const float* a = (const float*)d_in[0];
    const float* b = (const float*)d_in[1];
    float* out = (float*)d_out;
    char* ws = (char*)d_ws;
    float* Q        = (float*)(ws);                                    // 16 MB (Q, then LG2 in place)
    float* Ahat     = (float*)(ws + (size_t)16 * 1024 * 1024);         // 4 MB
    float* Bhat     = (float*)(ws + (size_t)20 * 1024 * 1024);         // 4 MB
    float* rowscale = (float*)(ws + (size_t)24 * 1024 * 1024);         // 8 KB
    int* permA      = (int*)(ws + (size_t)24 * 1024 * 1024 + 8192);    // 8 KB
    int* permB      = (int*)(ws + (size_t)24 * 1024 * 1024 + 16384);   // 8 KB

    argsort_kernel<<<dim3(8, 2), 256, 0, stream>>>(a, b, permA, permB);
    norm_kernel<<<dim3(2048, 2), 128, 0, stream>>>(a, b, permA, permB, Ahat, Bhat);
    gemm_kernel<<<dim3(32, 32), 256, 0, stream>>>(Ahat, Bhat, Q);
    rowstat_kernel<<<2048, 256, 0, stream>>>(Q, rowscale);
    lg_kernel<<<4096, 256, 0, stream>>>(Q, rowscale);
    dp_kernel<<<1, 512, 0, stream>>>(Q, rowscale, out);
}